// Round 15
// baseline (3831.264 us; speedup 1.0000x reference)
//
#include <hip/hip_runtime.h>
#include <cmath>

#define NHEADS 12
#define NTOK   257
#define BATCH  32
#define ROWS   (BATCH*NTOK)   // 8224
#define PROWS  (BATCH*256)    // 8192
#define GTPAD  288            // padded key length for Vt

typedef __attribute__((ext_vector_type(8))) short short8;
typedef __attribute__((ext_vector_type(8))) unsigned short u16x8;
typedef __attribute__((ext_vector_type(4))) float f32x4;

__device__ __forceinline__ unsigned short f2bf(float f) {
    unsigned u = __float_as_uint(f);
    unsigned r = (u + 0x7FFFu + ((u >> 16) & 1u)) >> 16;
    return (unsigned short)r;
}
__device__ __forceinline__ float b2f(unsigned short us) {
    return __uint_as_float((unsigned)us << 16);
}
__device__ __forceinline__ void gload16(const void* g, void* l) {
    __builtin_amdgcn_global_load_lds(
        (const __attribute__((address_space(1))) void*)g,
        (__attribute__((address_space(3))) void*)l, 16, 0, 0);
}
// tanh-form GELU (|err| ~1e-3; ~10 VALU ops vs ~30 for libm erff)
__device__ __forceinline__ float gelu_f(float x) {
    float y = 0.7978845608f * (x + 0.044715f * x * x * x);
    float e = __expf(2.f * y);
    float t = 1.f - 2.f / (e + 1.f);
    return 0.5f * x * (1.f + t);
}

// ---------------------------------------------------------------------------
// bf16 MFMA GEMM (128x128 tile): 4 waves (2x2), wave 64x64, BK=32 DOUBLE-
// buffered (32KB LDS total -> ~5 blocks/CU residency AND stage-ahead with a
// single barrier per K-tile — m97 recipe). 16x16x32 MFMA, 2-bit XOR swizzle
// (<=4-way read alias, hidden off critical path per m233/m252), XCD remap.
// VT: for col>=1536 (V part of qkv), write transposed into vt[bh][d][GTPAD].
// ---------------------------------------------------------------------------
template<bool BIAS, bool GELU, bool RES, bool SKIPAR, bool OUTBF, bool VT>
__global__ __launch_bounds__(256) void gemm_bf16(
    const unsigned short* __restrict__ A, const unsigned short* __restrict__ W,
    const float* __restrict__ bias, void* __restrict__ outv,
    unsigned short* __restrict__ vt,
    int M, int N, int K)
{
    __shared__ unsigned short As[2][128 * 32];
    __shared__ unsigned short Bs[2][128 * 32];
    const int tid = threadIdx.x;
    const int lane = tid & 63, wid = tid >> 6;
    const int wr = wid >> 1, wc = wid & 1;

    // bijective XCD-chunked remap (m204)
    const int gx = gridDim.x;
    const int nwg = gx * gridDim.y;
    const int orig = blockIdx.y * gx + blockIdx.x;
    const int q8 = nwg >> 3, r8 = nwg & 7;
    const int xcd = orig & 7, lid = orig >> 3;
    const int wg = (xcd < r8 ? xcd * (q8 + 1) : r8 * (q8 + 1) + (xcd - r8) * q8) + lid;
    const int bn = (wg % gx) * 128;
    const int bm = (wg / gx) * 128;

    f32x4 acc[4][4];
    #pragma unroll
    for (int i = 0; i < 4; i++)
        #pragma unroll
        for (int j = 0; j < 4; j++) acc[i][j] = (f32x4)0.f;

    const int l15 = lane & 15;
    const int lg  = lane >> 4;             // k-chunk 0..3
    const int sw3 = l15 & 3;               // 2-bit row-XOR for reads

    // staging: f = it*256 + tid in [0,512): row = f>>2 (0..127), phys chunk
    // f&3, global chunk = (f&3)^(row&3) (inverse-swizzled source). 2 loads
    // per matrix per thread per K-tile.
    auto stage = [&](int buf, int k0) {
        #pragma unroll
        for (int it = 0; it < 2; it++) {
            int f = it * 256 + tid;
            int row = f >> 2;
            int gc = (f & 3) ^ (row & 3);
            gload16(A + (size_t)(bm + row) * K + k0 + gc * 8, &As[buf][f * 8]);
            gload16(W + (size_t)(bn + row) * K + k0 + gc * 8, &Bs[buf][f * 8]);
        }
    };

    const int nt = K >> 5;
    stage(0, 0);
    __syncthreads();

    int buf = 0;
    for (int t = 0; t < nt; t++) {
        if (t + 1 < nt) stage(buf ^ 1, (t + 1) << 5);
        short8 af[4], bf[4];
        #pragma unroll
        for (int i = 0; i < 4; i++) {
            int row = wr * 64 + i * 16 + l15;
            af[i] = *(const short8*)&As[buf][row * 32 + (lg ^ sw3) * 8];
        }
        #pragma unroll
        for (int j = 0; j < 4; j++) {
            int row = wc * 64 + j * 16 + l15;
            bf[j] = *(const short8*)&Bs[buf][row * 32 + (lg ^ sw3) * 8];
        }
        #pragma unroll
        for (int i = 0; i < 4; i++)
            #pragma unroll
            for (int j = 0; j < 4; j++)
                acc[i][j] = __builtin_amdgcn_mfma_f32_16x16x32_bf16(af[i], bf[j], acc[i][j], 0, 0, 0);
        __syncthreads();
        buf ^= 1;
    }

    float bcol[4];
    #pragma unroll
    for (int j = 0; j < 4; j++)
        bcol[j] = BIAS ? bias[bn + wc * 64 + j * 16 + l15] : 0.f;

    #pragma unroll
    for (int i = 0; i < 4; i++) {
        #pragma unroll
        for (int r = 0; r < 4; r++) {
            int row = bm + wr * 64 + i * 16 + lg * 4 + r;
            if (row >= M) continue;
            if (SKIPAR && (row % NTOK) == (NTOK - 1)) continue;
            int bb = 0, tok = 0;
            if (VT) { bb = row / NTOK; tok = row - bb * NTOK; }
            #pragma unroll
            for (int j = 0; j < 4; j++) {
                int col = bn + wc * 64 + j * 16 + l15;
                float v = acc[i][j][r] + bcol[j];
                if (GELU) v = gelu_f(v);
                size_t idx = (size_t)row * N + col;
                if (OUTBF) {
                    if (VT && col >= 1536) {
                        int c = col - 1536;
                        int nh = c >> 6, d = c & 63;
                        vt[(size_t)((bb * NHEADS + nh) * 64 + d) * GTPAD + tok] = f2bf(v);
                    } else {
                        ((unsigned short*)outv)[idx] = f2bf(v);
                    }
                } else {
                    float* o = (float*)outv;
                    if (RES) o[idx] += v; else o[idx] = v;
                }
            }
        }
    }
}

// ---------------------------------------------------------------------------
// Zero the Vt pad region (tokens 256..287). Launched ONCE per call.
// ---------------------------------------------------------------------------
__global__ __launch_bounds__(256) void zero_vt_pad(unsigned short* __restrict__ vt)
{
    int t = blockIdx.x * 256 + threadIdx.x;      // 0 .. 384*64*4-1
    int bhd = t >> 2, ch = t & 3;
    *(uint4*)(vt + (size_t)bhd * GTPAD + 256 + ch * 8) = make_uint4(0u, 0u, 0u, 0u);
}

// ---------------------------------------------------------------------------
// LayerNorm: one wave per row of 768. Input fp32, output fp32 or bf16.
// ---------------------------------------------------------------------------
template<bool OUTBF>
__global__ __launch_bounds__(256) void ln_kernel(
    const float* __restrict__ in, void* __restrict__ outv,
    const float* __restrict__ g, const float* __restrict__ bparm, int rows)
{
    int gw = blockIdx.x * 4 + (threadIdx.x >> 6);
    int lane = threadIdx.x & 63;
    if (gw >= rows) return;
    const float* x = in + (size_t)gw * 768;
    float4 v[3];
    #pragma unroll
    for (int i = 0; i < 3; i++) v[i] = *(const float4*)(x + i * 256 + lane * 4);
    float s = 0.f;
    #pragma unroll
    for (int i = 0; i < 3; i++) s += v[i].x + v[i].y + v[i].z + v[i].w;
    #pragma unroll
    for (int off = 32; off >= 1; off >>= 1) s += __shfl_xor(s, off, 64);
    float mu = s * (1.f / 768.f);
    float q = 0.f;
    #pragma unroll
    for (int i = 0; i < 3; i++) {
        float dx = v[i].x - mu, dy = v[i].y - mu, dz = v[i].z - mu, dw = v[i].w - mu;
        q += dx * dx + dy * dy + dz * dz + dw * dw;
    }
    #pragma unroll
    for (int off = 32; off >= 1; off >>= 1) q += __shfl_xor(q, off, 64);
    float rstd = rsqrtf(q * (1.f / 768.f) + 1e-5f);
    #pragma unroll
    for (int i = 0; i < 3; i++) {
        float4 gg = *(const float4*)(g + i * 256 + lane * 4);
        float4 bb = *(const float4*)(bparm + i * 256 + lane * 4);
        float rx = (v[i].x - mu) * rstd * gg.x + bb.x;
        float ry = (v[i].y - mu) * rstd * gg.y + bb.y;
        float rz = (v[i].z - mu) * rstd * gg.z + bb.z;
        float rw = (v[i].w - mu) * rstd * gg.w + bb.w;
        if (OUTBF) {
            ushort4 u;
            u.x = f2bf(rx); u.y = f2bf(ry); u.z = f2bf(rz); u.w = f2bf(rw);
            *(ushort4*)((unsigned short*)outv + (size_t)gw * 768 + i * 256 + lane * 4) = u;
        } else {
            *(float4*)((float*)outv + (size_t)gw * 768 + i * 256 + lane * 4) =
                make_float4(rx, ry, rz, rw);
        }
    }
}

// ---------------------------------------------------------------------------
__global__ __launch_bounds__(256) void f2b_kernel(
    const float* __restrict__ in, unsigned short* __restrict__ out, int n4)
{
    int i = blockIdx.x * 256 + threadIdx.x;
    if (i >= n4) return;
    float4 v = ((const float4*)in)[i];
    ushort4 u;
    u.x = f2bf(v.x); u.y = f2bf(v.y); u.z = f2bf(v.z); u.w = f2bf(v.w);
    ((ushort4*)out)[i] = u;
}

// ---------------------------------------------------------------------------
__global__ __launch_bounds__(256) void gather_patches(
    const float* __restrict__ x, unsigned short* __restrict__ A)
{
    int row = blockIdx.x;                 // 0..8191
    int b = row >> 8;
    int pp = row & 255;
    int ph = pp >> 4, pw = pp & 15;
    const float* xb = x + (size_t)b * 196608;
    for (int e = threadIdx.x; e < 768; e += 256) {
        int c = e >> 8;
        int r = e & 255;
        int p = r >> 4, q = r & 15;
        A[(size_t)row * 768 + e] = f2bf(xb[(size_t)c * 65536 + (ph * 16 + p) * 256 + pw * 16 + q]);
    }
}

// ---------------------------------------------------------------------------
__global__ __launch_bounds__(256) void build_h_kernel(
    const unsigned short* __restrict__ lnp, const float* __restrict__ pos,
    const float* __restrict__ artok, const float* __restrict__ aspect,
    float* __restrict__ h)
{
    int row = blockIdx.x;                 // 0..8223
    int b = row / NTOK;
    int t = row - b * NTOK;
    float* hp = h + (size_t)row * 768;
    int e = threadIdx.x;
    if (t < 256) {
        const unsigned short* lp = lnp + ((size_t)b * 256 + t) * 768;
        const float* pp = pos + (size_t)t * 768;
        #pragma unroll
        for (int i = 0; i < 3; i++) { int c = e + i * 256; hp[c] = b2f(lp[c]) + pp[c]; }
    } else {
        float f = 1.0f + aspect[b] * 0.1f;
        const float* pp = pos + (size_t)256 * 768;
        #pragma unroll
        for (int i = 0; i < 3; i++) { int c = e + i * 256; hp[c] = artok[c] * f + pp[c]; }
    }
}

// ---------------------------------------------------------------------------
// Local windowed attention, MFMA. One wave per (b,head,image-row h0).
// ---------------------------------------------------------------------------
__global__ __launch_bounds__(256) void local_attn_mfma(
    const unsigned short* __restrict__ qkv, const unsigned short* __restrict__ vt,
    unsigned short* __restrict__ out)
{
    __shared__ unsigned short P[4][16 * 136];        // per-wave P slab, stride 272B
    const int wid = threadIdx.x >> 6, lane = threadIdx.x & 63;
    const int gw = blockIdx.x * 4 + wid;
    const int bh = gw >> 4, h0 = gw & 15;
    const int b = bh / NHEADS, nh = bh % NHEADS;
    const int l15 = lane & 15, lg = lane >> 4;
    const unsigned short* base = qkv + (size_t)b * NTOK * 2304 + nh * 64;
    const unsigned short* vtb = vt + (size_t)bh * 64 * GTPAD;
    unsigned short* Pw = P[wid];

    const int qtok = h0 * 16 + l15;
    short8 qf0 = *(const short8*)(base + (size_t)qtok * 2304 + lg * 8);
    short8 qf1 = *(const short8*)(base + (size_t)qtok * 2304 + 32 + lg * 8);

    int r0 = h0 - 3; r0 = r0 < 0 ? 0 : (r0 > 8 ? 8 : r0);   // 8 key rows r0..r0+7

    f32x4 s[8];
    #pragma unroll
    for (int i = 0; i < 8; i++) {
        const unsigned short* kr = base + (size_t)((r0 + i) * 16 + l15) * 2304 + 768;
        short8 kf0 = *(const short8*)(kr + lg * 8);
        short8 kf1 = *(const short8*)(kr + 32 + lg * 8);
        f32x4 z = (f32x4)0.f;
        z = __builtin_amdgcn_mfma_f32_16x16x32_bf16(kf0, qf0, z, 0, 0, 0);
        z = __builtin_amdgcn_mfma_f32_16x16x32_bf16(kf1, qf1, z, 0, 0, 0);
        s[i] = z;
    }

    const int vlo = l15 - 3 < 0 ? 0 : l15 - 3;
    const int vhi = l15 + 3 > 15 ? 15 : l15 + 3;
    const int rlo = h0 - 3 < 0 ? 0 : h0 - 3;
    const int rhi = h0 + 3 > 15 ? 15 : h0 + 3;
    const int n_oob = 49 - (rhi - rlo + 1) * (vhi - vlo + 1);
    float m = n_oob > 0 ? 0.f : -1e30f;
    float sv[32];
    #pragma unroll
    for (int i = 0; i < 8; i++) {
        int kh = r0 + i;
        bool rowok = (kh >= rlo) && (kh <= rhi);
        #pragma unroll
        for (int r = 0; r < 4; r++) {
            int kw = lg * 4 + r;
            bool ok = rowok && (kw >= vlo) && (kw <= vhi);
            float xx = ok ? s[i][r] * 0.125f : -1e30f;
            sv[i * 4 + r] = xx;
            m = fmaxf(m, xx);
        }
    }
    m = fmaxf(m, __shfl_xor(m, 16, 64));
    m = fmaxf(m, __shfl_xor(m, 32, 64));
    float tsum = 0.f;
    #pragma unroll
    for (int i = 0; i < 8; i++) {
        float p0 = __expf(sv[i * 4 + 0] - m);
        float p1 = __expf(sv[i * 4 + 1] - m);
        float p2 = __expf(sv[i * 4 + 2] - m);
        float p3 = __expf(sv[i * 4 + 3] - m);
        tsum += p0 + p1 + p2 + p3;
        unsigned u0 = (unsigned)f2bf(p0) | ((unsigned)f2bf(p1) << 16);
        unsigned u1 = (unsigned)f2bf(p2) | ((unsigned)f2bf(p3) << 16);
        *(uint2*)((char*)Pw + l15 * 272 + i * 32 + lg * 8) = make_uint2(u0, u1);
    }
    tsum += __shfl_xor(tsum, 16, 64);
    tsum += __shfl_xor(tsum, 32, 64);
    float denom = tsum + (float)n_oob * __expf(-m);
    __syncthreads();

    f32x4 acc[4];
    #pragma unroll
    for (int d = 0; d < 4; d++) acc[d] = (f32x4)0.f;
    #pragma unroll
    for (int kt = 0; kt < 128; kt += 32) {
        short8 pf = *(const short8*)((char*)Pw + l15 * 272 + kt * 2 + lg * 16);
        #pragma unroll
        for (int d = 0; d < 4; d++) {
            short8 vf = *(const short8*)(vtb + (size_t)(d * 16 + l15) * GTPAD + r0 * 16 + kt + lg * 8);
            acc[d] = __builtin_amdgcn_mfma_f32_16x16x32_bf16(vf, pf, acc[d], 0, 0, 0);
        }
    }

    float inv = 1.f / denom;
    unsigned short* op = out + ((size_t)b * NTOK + qtok) * 768 + nh * 64;
    #pragma unroll
    for (int d = 0; d < 4; d++) {
        ushort4 o;
        o.x = f2bf(acc[d][0] * inv);
        o.y = f2bf(acc[d][1] * inv);
        o.z = f2bf(acc[d][2] * inv);
        o.w = f2bf(acc[d][3] * inv);
        *(ushort4*)(op + d * 16 + lg * 4) = o;
    }
}

// ---------------------------------------------------------------------------
// Global attention, MFMA flash. One wave per (head, 16-query tile).
// ---------------------------------------------------------------------------
__global__ __launch_bounds__(64) void global_attn_mfma(
    const unsigned short* __restrict__ qkv, const unsigned short* __restrict__ vt,
    unsigned short* __restrict__ out)
{
    __shared__ uint4 Pbuf[80];                       // 16 q * 40 ushort (pad)
    unsigned short* P = (unsigned short*)Pbuf;
    const int blk = blockIdx.x;
    const int bh = blk / 17, qt = blk % 17;
    const int b = bh / NHEADS, nh = bh % NHEADS;
    const int lane = threadIdx.x;
    const int l15 = lane & 15, lg = lane >> 4;
    const unsigned short* base = qkv + (size_t)b * NTOK * 2304 + nh * 64;
    const unsigned short* vtb = vt + (size_t)bh * 64 * GTPAD;

    int qrow = qt * 16 + l15;
    const bool qvalid = qrow < NTOK;
    if (!qvalid) qrow = NTOK - 1;
    short8 qf[2];
    qf[0] = *(const short8*)(base + (size_t)qrow * 2304 + lg * 8);
    qf[1] = *(const short8*)(base + (size_t)qrow * 2304 + 32 + lg * 8);

    f32x4 acc[4];
    #pragma unroll
    for (int i = 0; i < 4; i++) acc[i] = (f32x4)0.f;
    float m = -1e30f, l = 0.f;

    for (int kt = 0; kt < GTPAD; kt += 32) {
        f32x4 s[2];
        #pragma unroll
        for (int hh = 0; hh < 2; hh++) {
            int krow = kt + hh * 16 + l15;
            if (krow > NTOK - 1) krow = NTOK - 1;
            short8 kf0 = *(const short8*)(base + (size_t)krow * 2304 + 768 + lg * 8);
            short8 kf1 = *(const short8*)(base + (size_t)krow * 2304 + 768 + 32 + lg * 8);
            f32x4 z = (f32x4)0.f;
            z = __builtin_amdgcn_mfma_f32_16x16x32_bf16(kf0, qf[0], z, 0, 0, 0);
            z = __builtin_amdgcn_mfma_f32_16x16x32_bf16(kf1, qf[1], z, 0, 0, 0);
            s[hh] = z;
        }
        float sv[8];
        float mt = -1e30f;
        #pragma unroll
        for (int hh = 0; hh < 2; hh++)
            #pragma unroll
            for (int r = 0; r < 4; r++) {
                int key = kt + hh * 16 + lg * 4 + r;
                float v = s[hh][r] * 0.125f;
                if (key >= NTOK) v = -1e30f;
                sv[hh * 4 + r] = v;
                mt = fmaxf(mt, v);
            }
        mt = fmaxf(mt, __shfl_xor(mt, 16, 64));
        mt = fmaxf(mt, __shfl_xor(mt, 32, 64));
        float mn = fmaxf(m, mt);
        float cf = __expf(m - mn);
        float tsum = 0.f;
        unsigned short pb[8];
        #pragma unroll
        for (int i = 0; i < 8; i++) {
            float p = __expf(sv[i] - mn);
            tsum += p;
            pb[i] = f2bf(p);
        }
        tsum += __shfl_xor(tsum, 16, 64);
        tsum += __shfl_xor(tsum, 32, 64);
        l = l * cf + tsum;
        m = mn;
        #pragma unroll
        for (int i = 0; i < 4; i++) acc[i] *= cf;

        unsigned u0 = (unsigned)pb[0] | ((unsigned)pb[1] << 16);
        unsigned u1 = (unsigned)pb[2] | ((unsigned)pb[3] << 16);
        unsigned u2 = (unsigned)pb[4] | ((unsigned)pb[5] << 16);
        unsigned u3 = (unsigned)pb[6] | ((unsigned)pb[7] << 16);
        *(uint2*)((char*)P + l15 * 80 + lg * 8)      = make_uint2(u0, u1);
        *(uint2*)((char*)P + l15 * 80 + 32 + lg * 8) = make_uint2(u2, u3);
        __syncthreads();
        short8 pf = *(const short8*)((char*)P + l15 * 80 + lg * 16);
        #pragma unroll
        for (int d = 0; d < 4; d++) {
            short8 vf = *(const short8*)(vtb + (size_t)(d * 16 + l15) * GTPAD + kt + lg * 8);
            acc[d] = __builtin_amdgcn_mfma_f32_16x16x32_bf16(vf, pf, acc[d], 0, 0, 0);
        }
        __syncthreads();
    }

    if (qvalid) {
        float inv = 1.f / l;
        unsigned short* op = out + ((size_t)b * NTOK + qrow) * 768 + nh * 64;
        #pragma unroll
        for (int d = 0; d < 4; d++) {
            ushort4 o;
            o.x = f2bf(acc[d][0] * inv);
            o.y = f2bf(acc[d][1] * inv);
            o.z = f2bf(acc[d][2] * inv);
            o.w = f2bf(acc[d][3] * inv);
            *(ushort4*)(op + d * 16 + lg * 4) = o;
        }
    }
}

// ---------------------------------------------------------------------------
extern "C" void kernel_launch(void* const* d_in, const int* in_sizes, int n_in,
                              void* d_out, int out_size, void* d_ws, size_t ws_size,
                              hipStream_t stream)
{
    const float* x       = (const float*)d_in[0];
    const float* aspect  = (const float*)d_in[1];
    const float* conv_w  = (const float*)d_in[2];
    const float* conv_b  = (const float*)d_in[3];
    const float* pe_g    = (const float*)d_in[4];
    const float* pe_b    = (const float*)d_in[5];
    const float* ar_tok  = (const float*)d_in[6];
    const float* pos     = (const float*)d_in[7];
    const float* ln1_g   = (const float*)d_in[8];
    const float* ln1_b   = (const float*)d_in[9];
    const float* ln2_g   = (const float*)d_in[10];
    const float* ln2_b   = (const float*)d_in[11];
    const float* loc_qkv_w  = (const float*)d_in[12];
    const float* loc_proj_w = (const float*)d_in[13];
    const float* loc_proj_b = (const float*)d_in[14];
    const float* glob_in_w  = (const float*)d_in[15];
    const float* glob_in_b  = (const float*)d_in[16];
    const float* glob_out_w = (const float*)d_in[17];
    const float* glob_out_b = (const float*)d_in[18];
    const float* mlp_w1  = (const float*)d_in[19];
    const float* mlp_b1  = (const float*)d_in[20];
    const float* mlp_w2  = (const float*)d_in[21];
    const float* mlp_b2  = (const float*)d_in[22];
    const float* fin_g   = (const float*)d_in[23];
    const float* fin_b   = (const float*)d_in[24];

    char* w = (char*)d_ws;
    float*          h     = (float*)w;                                   // 25,264,128 B
    unsigned short* lnb   = (unsigned short*)(w + 25264128);             // 12,632,064 B
    unsigned short* qkvb  = (unsigned short*)(w + 37896192);             // 37,896,192 B
    unsigned short* attnb = (unsigned short*)(w + 75792384);             // 12,632,064 B
    unsigned short* mlpb  = (unsigned short*)(w + 88424448);             // 50,528,256 B
    float*          pembf = (float*)mlpb;                                // aliased (pre-loop only)
    unsigned short* vtb   = (unsigned short*)(w + 124796928);            // tail of mlpb, 14.2 MB
    char* wp = w + 138952704;
    unsigned short* wconv  = (unsigned short*)wp;               wp += 1179648;
    unsigned short* wlqkv  = (unsigned short*)wp;               wp += 21233664;
    unsigned short* wlproj = (unsigned short*)wp;               wp += 7077888;
    unsigned short* wgin   = (unsigned short*)wp;               wp += 21233664;
    unsigned short* wgout  = (unsigned short*)wp;               wp += 7077888;
    unsigned short* wm1    = (unsigned short*)wp;               wp += 56623104;
    unsigned short* wm2    = (unsigned short*)wp;               wp += 56623104;

    auto cvt = [&](const float* src, unsigned short* dst, int n) {
        int n4 = n / 4;
        f2b_kernel<<<(n4 + 255) / 256, 256, 0, stream>>>(src, dst, n4);
    };
    cvt(conv_w,     wconv,  768 * 768);
    cvt(loc_qkv_w,  wlqkv,  6 * 2304 * 768);
    cvt(loc_proj_w, wlproj, 6 * 768 * 768);
    cvt(glob_in_w,  wgin,   6 * 2304 * 768);
    cvt(glob_out_w, wgout,  6 * 768 * 768);
    cvt(mlp_w1,     wm1,    12 * 3072 * 768);
    cvt(mlp_w2,     wm2,    12 * 768 * 3072);

    // ---- patch embed ----
    gather_patches<<<PROWS, 256, 0, stream>>>(x, qkvb);
    gemm_bf16<true, false, false, false, false, false><<<dim3(6, 64), 256, 0, stream>>>(
        qkvb, wconv, conv_b, pembf, nullptr, PROWS, 768, 768);
    ln_kernel<true><<<PROWS / 4, 256, 0, stream>>>(pembf, attnb, pe_g, pe_b, PROWS);
    build_h_kernel<<<ROWS, 256, 0, stream>>>(attnb, pos, ar_tok, aspect, h);
    zero_vt_pad<<<384, 256, 0, stream>>>(vtb);   // pad tokens stay 0 across layers

    const int mt = (ROWS + 127) / 128;    // 65
    for (int i = 0; i < 12; i++) {
        int half = i / 2;
        ln_kernel<true><<<(ROWS + 3) / 4, 256, 0, stream>>>(h, lnb, ln1_g + i * 768, ln1_b + i * 768, ROWS);
        if ((i & 1) == 0) {
            gemm_bf16<false, false, false, false, true, true><<<dim3(18, mt), 256, 0, stream>>>(
                lnb, wlqkv + (size_t)half * 2304 * 768, nullptr, qkvb, vtb, ROWS, 2304, 768);
            local_attn_mfma<<<BATCH * NHEADS * 16 / 4, 256, 0, stream>>>(qkvb, vtb, attnb);
            gemm_bf16<true, false, true, true, false, false><<<dim3(6, mt), 256, 0, stream>>>(
                attnb, wlproj + (size_t)half * 768 * 768, loc_proj_b + half * 768, h, nullptr, ROWS, 768, 768);
        } else {
            gemm_bf16<true, false, false, false, true, true><<<dim3(18, mt), 256, 0, stream>>>(
                lnb, wgin + (size_t)half * 2304 * 768, glob_in_b + half * 2304, qkvb, vtb, ROWS, 2304, 768);
            global_attn_mfma<<<BATCH * NHEADS * 17, 64, 0, stream>>>(qkvb, vtb, attnb);
            gemm_bf16<true, false, true, false, false, false><<<dim3(6, mt), 256, 0, stream>>>(
                attnb, wgout + (size_t)half * 768 * 768, glob_out_b + half * 768, h, nullptr, ROWS, 768, 768);
        }
        ln_kernel<true><<<(ROWS + 3) / 4, 256, 0, stream>>>(h, lnb, ln2_g + i * 768, ln2_b + i * 768, ROWS);
        gemm_bf16<true, true, false, false, true, false><<<dim3(24, mt), 256, 0, stream>>>(
            lnb, wm1 + (size_t)i * 3072 * 768, mlp_b1 + i * 3072, mlpb, nullptr, ROWS, 3072, 768);
        gemm_bf16<true, false, true, false, false, false><<<dim3(6, mt), 256, 0, stream>>>(
            mlpb, wm2 + (size_t)i * 768 * 3072, mlp_b2 + i * 768, h, nullptr, ROWS, 768, 3072);
    }
    ln_kernel<false><<<(ROWS + 3) / 4, 256, 0, stream>>>(h, (float*)d_out, fin_g, fin_b, ROWS);
}

// Round 16
// 3624.207 us; speedup vs baseline: 1.0571x; 1.0571x over previous
//
#include <hip/hip_runtime.h>
#include <cmath>

#define NHEADS 12
#define NTOK   257
#define BATCH  32
#define ROWS   (BATCH*NTOK)   // 8224
#define PROWS  (BATCH*256)    // 8192
#define GTPAD  288            // padded key length for Vt

typedef __attribute__((ext_vector_type(8))) short short8;
typedef __attribute__((ext_vector_type(8))) unsigned short u16x8;
typedef __attribute__((ext_vector_type(4))) float f32x4;

__device__ __forceinline__ unsigned short f2bf(float f) {
    unsigned u = __float_as_uint(f);
    unsigned r = (u + 0x7FFFu + ((u >> 16) & 1u)) >> 16;
    return (unsigned short)r;
}
__device__ __forceinline__ float b2f(unsigned short us) {
    return __uint_as_float((unsigned)us << 16);
}
__device__ __forceinline__ void gload16(const void* g, void* l) {
    __builtin_amdgcn_global_load_lds(
        (const __attribute__((address_space(1))) void*)g,
        (__attribute__((address_space(3))) void*)l, 16, 0, 0);
}
// tanh-form GELU (|err| ~1e-3; ~10 VALU ops vs ~30 for libm erff)
__device__ __forceinline__ float gelu_f(float x) {
    float y = 0.7978845608f * (x + 0.044715f * x * x * x);
    float e = __expf(2.f * y);
    float t = 1.f - 2.f / (e + 1.f);
    return 0.5f * x * (1.f + t);
}

// ---------------------------------------------------------------------------
// bf16 MFMA GEMM (128x128 tile): 4 waves (2x2), wave 64x64, BK=64,
// SINGLE-buffered LDS (32KB -> ~5 blocks/CU residency; inter-block TLP hides
// the per-tile staging drain — best measured variant, R14). 16x16x32 MFMA,
// conflict-free XOR swizzle, XCD remap.
// VT: for col>=1536 (V part of qkv), write transposed into vt[bh][d][GTPAD].
// ---------------------------------------------------------------------------
template<bool BIAS, bool GELU, bool RES, bool SKIPAR, bool OUTBF, bool VT>
__global__ __launch_bounds__(256) void gemm_bf16(
    const unsigned short* __restrict__ A, const unsigned short* __restrict__ W,
    const float* __restrict__ bias, void* __restrict__ outv,
    unsigned short* __restrict__ vt,
    int M, int N, int K)
{
    __shared__ unsigned short As[128 * 64];
    __shared__ unsigned short Bs[128 * 64];
    const int tid = threadIdx.x;
    const int lane = tid & 63, wid = tid >> 6;
    const int wr = wid >> 1, wc = wid & 1;

    // bijective XCD-chunked remap (m204)
    const int gx = gridDim.x;
    const int nwg = gx * gridDim.y;
    const int orig = blockIdx.y * gx + blockIdx.x;
    const int q8 = nwg >> 3, r8 = nwg & 7;
    const int xcd = orig & 7, lid = orig >> 3;
    const int wg = (xcd < r8 ? xcd * (q8 + 1) : r8 * (q8 + 1) + (xcd - r8) * q8) + lid;
    const int bn = (wg % gx) * 128;
    const int bm = (wg / gx) * 128;

    f32x4 acc[4][4];
    #pragma unroll
    for (int i = 0; i < 4; i++)
        #pragma unroll
        for (int j = 0; j < 4; j++) acc[i][j] = (f32x4)0.f;

    const int l15 = lane & 15;
    const int lg  = lane >> 4;
    const int sw  = l15 & 7;

    const int nt = K >> 6;
    for (int t = 0; t < nt; t++) {
        int k0 = t << 6;
        #pragma unroll
        for (int it = 0; it < 4; it++) {
            int f = it * 256 + tid;
            int row = f >> 3;
            int gc = (f & 7) ^ (row & 7);
            gload16(A + (size_t)(bm + row) * K + k0 + gc * 8, &As[f * 8]);
            gload16(W + (size_t)(bn + row) * K + k0 + gc * 8, &Bs[f * 8]);
        }
        __syncthreads();
        #pragma unroll
        for (int kk = 0; kk < 2; kk++) {
            short8 af[4], bf[4];
            #pragma unroll
            for (int i = 0; i < 4; i++) {
                int row = wr * 64 + i * 16 + l15;
                af[i] = *(const short8*)&As[row * 64 + (((kk * 4 + lg) ^ sw)) * 8];
            }
            #pragma unroll
            for (int j = 0; j < 4; j++) {
                int row = wc * 64 + j * 16 + l15;
                bf[j] = *(const short8*)&Bs[row * 64 + (((kk * 4 + lg) ^ sw)) * 8];
            }
            #pragma unroll
            for (int i = 0; i < 4; i++)
                #pragma unroll
                for (int j = 0; j < 4; j++)
                    acc[i][j] = __builtin_amdgcn_mfma_f32_16x16x32_bf16(af[i], bf[j], acc[i][j], 0, 0, 0);
        }
        __syncthreads();
    }

    float bcol[4];
    #pragma unroll
    for (int j = 0; j < 4; j++)
        bcol[j] = BIAS ? bias[bn + wc * 64 + j * 16 + l15] : 0.f;

    #pragma unroll
    for (int i = 0; i < 4; i++) {
        #pragma unroll
        for (int r = 0; r < 4; r++) {
            int row = bm + wr * 64 + i * 16 + lg * 4 + r;
            if (row >= M) continue;
            if (SKIPAR && (row % NTOK) == (NTOK - 1)) continue;
            int bb = 0, tok = 0;
            if (VT) { bb = row / NTOK; tok = row - bb * NTOK; }
            #pragma unroll
            for (int j = 0; j < 4; j++) {
                int col = bn + wc * 64 + j * 16 + l15;
                float v = acc[i][j][r] + bcol[j];
                if (GELU) v = gelu_f(v);
                size_t idx = (size_t)row * N + col;
                if (OUTBF) {
                    if (VT && col >= 1536) {
                        int c = col - 1536;
                        int nh = c >> 6, d = c & 63;
                        vt[(size_t)((bb * NHEADS + nh) * 64 + d) * GTPAD + tok] = f2bf(v);
                    } else {
                        ((unsigned short*)outv)[idx] = f2bf(v);
                    }
                } else {
                    float* o = (float*)outv;
                    if (RES) o[idx] += v; else o[idx] = v;
                }
            }
        }
    }
}

// ---------------------------------------------------------------------------
// Zero the Vt pad region (tokens 256..287). Launched ONCE per call.
// ---------------------------------------------------------------------------
__global__ __launch_bounds__(256) void zero_vt_pad(unsigned short* __restrict__ vt)
{
    int t = blockIdx.x * 256 + threadIdx.x;      // 0 .. 384*64*4-1
    int bhd = t >> 2, ch = t & 3;
    *(uint4*)(vt + (size_t)bhd * GTPAD + 256 + ch * 8) = make_uint4(0u, 0u, 0u, 0u);
}

// ---------------------------------------------------------------------------
// LayerNorm: one wave per row of 768. Input fp32, output fp32 or bf16.
// ---------------------------------------------------------------------------
template<bool OUTBF>
__global__ __launch_bounds__(256) void ln_kernel(
    const float* __restrict__ in, void* __restrict__ outv,
    const float* __restrict__ g, const float* __restrict__ bparm, int rows)
{
    int gw = blockIdx.x * 4 + (threadIdx.x >> 6);
    int lane = threadIdx.x & 63;
    if (gw >= rows) return;
    const float* x = in + (size_t)gw * 768;
    float4 v[3];
    #pragma unroll
    for (int i = 0; i < 3; i++) v[i] = *(const float4*)(x + i * 256 + lane * 4);
    float s = 0.f;
    #pragma unroll
    for (int i = 0; i < 3; i++) s += v[i].x + v[i].y + v[i].z + v[i].w;
    #pragma unroll
    for (int off = 32; off >= 1; off >>= 1) s += __shfl_xor(s, off, 64);
    float mu = s * (1.f / 768.f);
    float q = 0.f;
    #pragma unroll
    for (int i = 0; i < 3; i++) {
        float dx = v[i].x - mu, dy = v[i].y - mu, dz = v[i].z - mu, dw = v[i].w - mu;
        q += dx * dx + dy * dy + dz * dz + dw * dw;
    }
    #pragma unroll
    for (int off = 32; off >= 1; off >>= 1) q += __shfl_xor(q, off, 64);
    float rstd = rsqrtf(q * (1.f / 768.f) + 1e-5f);
    #pragma unroll
    for (int i = 0; i < 3; i++) {
        float4 gg = *(const float4*)(g + i * 256 + lane * 4);
        float4 bb = *(const float4*)(bparm + i * 256 + lane * 4);
        float rx = (v[i].x - mu) * rstd * gg.x + bb.x;
        float ry = (v[i].y - mu) * rstd * gg.y + bb.y;
        float rz = (v[i].z - mu) * rstd * gg.z + bb.z;
        float rw = (v[i].w - mu) * rstd * gg.w + bb.w;
        if (OUTBF) {
            ushort4 u;
            u.x = f2bf(rx); u.y = f2bf(ry); u.z = f2bf(rz); u.w = f2bf(rw);
            *(ushort4*)((unsigned short*)outv + (size_t)gw * 768 + i * 256 + lane * 4) = u;
        } else {
            *(float4*)((float*)outv + (size_t)gw * 768 + i * 256 + lane * 4) =
                make_float4(rx, ry, rz, rw);
        }
    }
}

// ---------------------------------------------------------------------------
__global__ __launch_bounds__(256) void f2b_kernel(
    const float* __restrict__ in, unsigned short* __restrict__ out, int n4)
{
    int i = blockIdx.x * 256 + threadIdx.x;
    if (i >= n4) return;
    float4 v = ((const float4*)in)[i];
    ushort4 u;
    u.x = f2bf(v.x); u.y = f2bf(v.y); u.z = f2bf(v.z); u.w = f2bf(v.w);
    ((ushort4*)out)[i] = u;
}

// ---------------------------------------------------------------------------
__global__ __launch_bounds__(256) void gather_patches(
    const float* __restrict__ x, unsigned short* __restrict__ A)
{
    int row = blockIdx.x;                 // 0..8191
    int b = row >> 8;
    int pp = row & 255;
    int ph = pp >> 4, pw = pp & 15;
    const float* xb = x + (size_t)b * 196608;
    for (int e = threadIdx.x; e < 768; e += 256) {
        int c = e >> 8;
        int r = e & 255;
        int p = r >> 4, q = r & 15;
        A[(size_t)row * 768 + e] = f2bf(xb[(size_t)c * 65536 + (ph * 16 + p) * 256 + pw * 16 + q]);
    }
}

// ---------------------------------------------------------------------------
__global__ __launch_bounds__(256) void build_h_kernel(
    const unsigned short* __restrict__ lnp, const float* __restrict__ pos,
    const float* __restrict__ artok, const float* __restrict__ aspect,
    float* __restrict__ h)
{
    int row = blockIdx.x;                 // 0..8223
    int b = row / NTOK;
    int t = row - b * NTOK;
    float* hp = h + (size_t)row * 768;
    int e = threadIdx.x;
    if (t < 256) {
        const unsigned short* lp = lnp + ((size_t)b * 256 + t) * 768;
        const float* pp = pos + (size_t)t * 768;
        #pragma unroll
        for (int i = 0; i < 3; i++) { int c = e + i * 256; hp[c] = b2f(lp[c]) + pp[c]; }
    } else {
        float f = 1.0f + aspect[b] * 0.1f;
        const float* pp = pos + (size_t)256 * 768;
        #pragma unroll
        for (int i = 0; i < 3; i++) { int c = e + i * 256; hp[c] = artok[c] * f + pp[c]; }
    }
}

// ---------------------------------------------------------------------------
// Local windowed attention, MFMA. One wave per (b,head,image-row h0).
// ---------------------------------------------------------------------------
__global__ __launch_bounds__(256) void local_attn_mfma(
    const unsigned short* __restrict__ qkv, const unsigned short* __restrict__ vt,
    unsigned short* __restrict__ out)
{
    __shared__ unsigned short P[4][16 * 136];        // per-wave P slab, stride 272B
    const int wid = threadIdx.x >> 6, lane = threadIdx.x & 63;
    const int gw = blockIdx.x * 4 + wid;
    const int bh = gw >> 4, h0 = gw & 15;
    const int b = bh / NHEADS, nh = bh % NHEADS;
    const int l15 = lane & 15, lg = lane >> 4;
    const unsigned short* base = qkv + (size_t)b * NTOK * 2304 + nh * 64;
    const unsigned short* vtb = vt + (size_t)bh * 64 * GTPAD;
    unsigned short* Pw = P[wid];

    const int qtok = h0 * 16 + l15;
    short8 qf0 = *(const short8*)(base + (size_t)qtok * 2304 + lg * 8);
    short8 qf1 = *(const short8*)(base + (size_t)qtok * 2304 + 32 + lg * 8);

    int r0 = h0 - 3; r0 = r0 < 0 ? 0 : (r0 > 8 ? 8 : r0);   // 8 key rows r0..r0+7

    f32x4 s[8];
    #pragma unroll
    for (int i = 0; i < 8; i++) {
        const unsigned short* kr = base + (size_t)((r0 + i) * 16 + l15) * 2304 + 768;
        short8 kf0 = *(const short8*)(kr + lg * 8);
        short8 kf1 = *(const short8*)(kr + 32 + lg * 8);
        f32x4 z = (f32x4)0.f;
        z = __builtin_amdgcn_mfma_f32_16x16x32_bf16(kf0, qf0, z, 0, 0, 0);
        z = __builtin_amdgcn_mfma_f32_16x16x32_bf16(kf1, qf1, z, 0, 0, 0);
        s[i] = z;
    }

    const int vlo = l15 - 3 < 0 ? 0 : l15 - 3;
    const int vhi = l15 + 3 > 15 ? 15 : l15 + 3;
    const int rlo = h0 - 3 < 0 ? 0 : h0 - 3;
    const int rhi = h0 + 3 > 15 ? 15 : h0 + 3;
    const int n_oob = 49 - (rhi - rlo + 1) * (vhi - vlo + 1);
    float m = n_oob > 0 ? 0.f : -1e30f;
    float sv[32];
    #pragma unroll
    for (int i = 0; i < 8; i++) {
        int kh = r0 + i;
        bool rowok = (kh >= rlo) && (kh <= rhi);
        #pragma unroll
        for (int r = 0; r < 4; r++) {
            int kw = lg * 4 + r;
            bool ok = rowok && (kw >= vlo) && (kw <= vhi);
            float xx = ok ? s[i][r] * 0.125f : -1e30f;
            sv[i * 4 + r] = xx;
            m = fmaxf(m, xx);
        }
    }
    m = fmaxf(m, __shfl_xor(m, 16, 64));
    m = fmaxf(m, __shfl_xor(m, 32, 64));
    float tsum = 0.f;
    #pragma unroll
    for (int i = 0; i < 8; i++) {
        float p0 = __expf(sv[i * 4 + 0] - m);
        float p1 = __expf(sv[i * 4 + 1] - m);
        float p2 = __expf(sv[i * 4 + 2] - m);
        float p3 = __expf(sv[i * 4 + 3] - m);
        tsum += p0 + p1 + p2 + p3;
        unsigned u0 = (unsigned)f2bf(p0) | ((unsigned)f2bf(p1) << 16);
        unsigned u1 = (unsigned)f2bf(p2) | ((unsigned)f2bf(p3) << 16);
        *(uint2*)((char*)Pw + l15 * 272 + i * 32 + lg * 8) = make_uint2(u0, u1);
    }
    tsum += __shfl_xor(tsum, 16, 64);
    tsum += __shfl_xor(tsum, 32, 64);
    float denom = tsum + (float)n_oob * __expf(-m);
    __syncthreads();

    f32x4 acc[4];
    #pragma unroll
    for (int d = 0; d < 4; d++) acc[d] = (f32x4)0.f;
    #pragma unroll
    for (int kt = 0; kt < 128; kt += 32) {
        short8 pf = *(const short8*)((char*)Pw + l15 * 272 + kt * 2 + lg * 16);
        #pragma unroll
        for (int d = 0; d < 4; d++) {
            short8 vf = *(const short8*)(vtb + (size_t)(d * 16 + l15) * GTPAD + r0 * 16 + kt + lg * 8);
            acc[d] = __builtin_amdgcn_mfma_f32_16x16x32_bf16(vf, pf, acc[d], 0, 0, 0);
        }
    }

    float inv = 1.f / denom;
    unsigned short* op = out + ((size_t)b * NTOK + qtok) * 768 + nh * 64;
    #pragma unroll
    for (int d = 0; d < 4; d++) {
        ushort4 o;
        o.x = f2bf(acc[d][0] * inv);
        o.y = f2bf(acc[d][1] * inv);
        o.z = f2bf(acc[d][2] * inv);
        o.w = f2bf(acc[d][3] * inv);
        *(ushort4*)(op + d * 16 + lg * 4) = o;
    }
}

// ---------------------------------------------------------------------------
// Global attention, MFMA flash. One wave per (head, 16-query tile).
// ---------------------------------------------------------------------------
__global__ __launch_bounds__(64) void global_attn_mfma(
    const unsigned short* __restrict__ qkv, const unsigned short* __restrict__ vt,
    unsigned short* __restrict__ out)
{
    __shared__ uint4 Pbuf[80];                       // 16 q * 40 ushort (pad)
    unsigned short* P = (unsigned short*)Pbuf;
    const int blk = blockIdx.x;
    const int bh = blk / 17, qt = blk % 17;
    const int b = bh / NHEADS, nh = bh % NHEADS;
    const int lane = threadIdx.x;
    const int l15 = lane & 15, lg = lane >> 4;
    const unsigned short* base = qkv + (size_t)b * NTOK * 2304 + nh * 64;
    const unsigned short* vtb = vt + (size_t)bh * 64 * GTPAD;

    int qrow = qt * 16 + l15;
    const bool qvalid = qrow < NTOK;
    if (!qvalid) qrow = NTOK - 1;
    short8 qf[2];
    qf[0] = *(const short8*)(base + (size_t)qrow * 2304 + lg * 8);
    qf[1] = *(const short8*)(base + (size_t)qrow * 2304 + 32 + lg * 8);

    f32x4 acc[4];
    #pragma unroll
    for (int i = 0; i < 4; i++) acc[i] = (f32x4)0.f;
    float m = -1e30f, l = 0.f;

    for (int kt = 0; kt < GTPAD; kt += 32) {
        f32x4 s[2];
        #pragma unroll
        for (int hh = 0; hh < 2; hh++) {
            int krow = kt + hh * 16 + l15;
            if (krow > NTOK - 1) krow = NTOK - 1;
            short8 kf0 = *(const short8*)(base + (size_t)krow * 2304 + 768 + lg * 8);
            short8 kf1 = *(const short8*)(base + (size_t)krow * 2304 + 768 + 32 + lg * 8);
            f32x4 z = (f32x4)0.f;
            z = __builtin_amdgcn_mfma_f32_16x16x32_bf16(kf0, qf[0], z, 0, 0, 0);
            z = __builtin_amdgcn_mfma_f32_16x16x32_bf16(kf1, qf[1], z, 0, 0, 0);
            s[hh] = z;
        }
        float sv[8];
        float mt = -1e30f;
        #pragma unroll
        for (int hh = 0; hh < 2; hh++)
            #pragma unroll
            for (int r = 0; r < 4; r++) {
                int key = kt + hh * 16 + lg * 4 + r;
                float v = s[hh][r] * 0.125f;
                if (key >= NTOK) v = -1e30f;
                sv[hh * 4 + r] = v;
                mt = fmaxf(mt, v);
            }
        mt = fmaxf(mt, __shfl_xor(mt, 16, 64));
        mt = fmaxf(mt, __shfl_xor(mt, 32, 64));
        float mn = fmaxf(m, mt);
        float cf = __expf(m - mn);
        float tsum = 0.f;
        unsigned short pb[8];
        #pragma unroll
        for (int i = 0; i < 8; i++) {
            float p = __expf(sv[i] - mn);
            tsum += p;
            pb[i] = f2bf(p);
        }
        tsum += __shfl_xor(tsum, 16, 64);
        tsum += __shfl_xor(tsum, 32, 64);
        l = l * cf + tsum;
        m = mn;
        #pragma unroll
        for (int i = 0; i < 4; i++) acc[i] *= cf;

        unsigned u0 = (unsigned)pb[0] | ((unsigned)pb[1] << 16);
        unsigned u1 = (unsigned)pb[2] | ((unsigned)pb[3] << 16);
        unsigned u2 = (unsigned)pb[4] | ((unsigned)pb[5] << 16);
        unsigned u3 = (unsigned)pb[6] | ((unsigned)pb[7] << 16);
        *(uint2*)((char*)P + l15 * 80 + lg * 8)      = make_uint2(u0, u1);
        *(uint2*)((char*)P + l15 * 80 + 32 + lg * 8) = make_uint2(u2, u3);
        __syncthreads();
        short8 pf = *(const short8*)((char*)P + l15 * 80 + lg * 16);
        #pragma unroll
        for (int d = 0; d < 4; d++) {
            short8 vf = *(const short8*)(vtb + (size_t)(d * 16 + l15) * GTPAD + kt + lg * 8);
            acc[d] = __builtin_amdgcn_mfma_f32_16x16x32_bf16(vf, pf, acc[d], 0, 0, 0);
        }
        __syncthreads();
    }

    if (qvalid) {
        float inv = 1.f / l;
        unsigned short* op = out + ((size_t)b * NTOK + qrow) * 768 + nh * 64;
        #pragma unroll
        for (int d = 0; d < 4; d++) {
            ushort4 o;
            o.x = f2bf(acc[d][0] * inv);
            o.y = f2bf(acc[d][1] * inv);
            o.z = f2bf(acc[d][2] * inv);
            o.w = f2bf(acc[d][3] * inv);
            *(ushort4*)(op + d * 16 + lg * 4) = o;
        }
    }
}

// ---------------------------------------------------------------------------
extern "C" void kernel_launch(void* const* d_in, const int* in_sizes, int n_in,
                              void* d_out, int out_size, void* d_ws, size_t ws_size,
                              hipStream_t stream)
{
    const float* x       = (const float*)d_in[0];
    const float* aspect  = (const float*)d_in[1];
    const float* conv_w  = (const float*)d_in[2];
    const float* conv_b  = (const float*)d_in[3];
    const float* pe_g    = (const float*)d_in[4];
    const float* pe_b    = (const float*)d_in[5];
    const float* ar_tok  = (const float*)d_in[6];
    const float* pos     = (const float*)d_in[7];
    const float* ln1_g   = (const float*)d_in[8];
    const float* ln1_b   = (const float*)d_in[9];
    const float* ln2_g   = (const float*)d_in[10];
    const float* ln2_b   = (const float*)d_in[11];
    const float* loc_qkv_w  = (const float*)d_in[12];
    const float* loc_proj_w = (const float*)d_in[13];
    const float* loc_proj_b = (const float*)d_in[14];
    const float* glob_in_w  = (const float*)d_in[15];
    const float* glob_in_b  = (const float*)d_in[16];
    const float* glob_out_w = (const float*)d_in[17];
    const float* glob_out_b = (const float*)d_in[18];
    const float* mlp_w1  = (const float*)d_in[19];
    const float* mlp_b1  = (const float*)d_in[20];
    const float* mlp_w2  = (const float*)d_in[21];
    const float* mlp_b2  = (const float*)d_in[22];
    const float* fin_g   = (const float*)d_in[23];
    const float* fin_b   = (const float*)d_in[24];

    char* w = (char*)d_ws;
    float*          h     = (float*)w;                                   // 25,264,128 B
    unsigned short* lnb   = (unsigned short*)(w + 25264128);             // 12,632,064 B
    unsigned short* qkvb  = (unsigned short*)(w + 37896192);             // 37,896,192 B
    unsigned short* attnb = (unsigned short*)(w + 75792384);             // 12,632,064 B
    unsigned short* mlpb  = (unsigned short*)(w + 88424448);             // 50,528,256 B
    float*          pembf = (float*)mlpb;                                // aliased (pre-loop only)
    unsigned short* vtb   = (unsigned short*)(w + 124796928);            // tail of mlpb, 14.2 MB
    char* wp = w + 138952704;
    unsigned short* wconv  = (unsigned short*)wp;               wp += 1179648;
    unsigned short* wlqkv  = (unsigned short*)wp;               wp += 21233664;
    unsigned short* wlproj = (unsigned short*)wp;               wp += 7077888;
    unsigned short* wgin   = (unsigned short*)wp;               wp += 21233664;
    unsigned short* wgout  = (unsigned short*)wp;               wp += 7077888;
    unsigned short* wm1    = (unsigned short*)wp;               wp += 56623104;
    unsigned short* wm2    = (unsigned short*)wp;               wp += 56623104;

    auto cvt = [&](const float* src, unsigned short* dst, int n) {
        int n4 = n / 4;
        f2b_kernel<<<(n4 + 255) / 256, 256, 0, stream>>>(src, dst, n4);
    };
    cvt(conv_w,     wconv,  768 * 768);
    cvt(loc_qkv_w,  wlqkv,  6 * 2304 * 768);
    cvt(loc_proj_w, wlproj, 6 * 768 * 768);
    cvt(glob_in_w,  wgin,   6 * 2304 * 768);
    cvt(glob_out_w, wgout,  6 * 768 * 768);
    cvt(mlp_w1,     wm1,    12 * 3072 * 768);
    cvt(mlp_w2,     wm2,    12 * 768 * 3072);

    // ---- patch embed ----
    gather_patches<<<PROWS, 256, 0, stream>>>(x, qkvb);
    gemm_bf16<true, false, false, false, false, false><<<dim3(6, 64), 256, 0, stream>>>(
        qkvb, wconv, conv_b, pembf, nullptr, PROWS, 768, 768);
    ln_kernel<true><<<PROWS / 4, 256, 0, stream>>>(pembf, attnb, pe_g, pe_b, PROWS);
    build_h_kernel<<<ROWS, 256, 0, stream>>>(attnb, pos, ar_tok, aspect, h);
    zero_vt_pad<<<384, 256, 0, stream>>>(vtb);   // pad tokens stay 0 across layers

    const int mt = (ROWS + 127) / 128;    // 65
    for (int i = 0; i < 12; i++) {
        int half = i / 2;
        ln_kernel<true><<<(ROWS + 3) / 4, 256, 0, stream>>>(h, lnb, ln1_g + i * 768, ln1_b + i * 768, ROWS);
        if ((i & 1) == 0) {
            gemm_bf16<false, false, false, false, true, true><<<dim3(18, mt), 256, 0, stream>>>(
                lnb, wlqkv + (size_t)half * 2304 * 768, nullptr, qkvb, vtb, ROWS, 2304, 768);
            local_attn_mfma<<<BATCH * NHEADS * 16 / 4, 256, 0, stream>>>(qkvb, vtb, attnb);
            gemm_bf16<true, false, true, true, false, false><<<dim3(6, mt), 256, 0, stream>>>(
                attnb, wlproj + (size_t)half * 768 * 768, loc_proj_b + half * 768, h, nullptr, ROWS, 768, 768);
        } else {
            gemm_bf16<true, false, false, false, true, true><<<dim3(18, mt), 256, 0, stream>>>(
                lnb, wgin + (size_t)half * 2304 * 768, glob_in_b + half * 2304, qkvb, vtb, ROWS, 2304, 768);
            global_attn_mfma<<<BATCH * NHEADS * 17, 64, 0, stream>>>(qkvb, vtb, attnb);
            gemm_bf16<true, false, true, false, false, false><<<dim3(6, mt), 256, 0, stream>>>(
                attnb, wgout + (size_t)half * 768 * 768, glob_out_b + half * 768, h, nullptr, ROWS, 768, 768);
        }
        ln_kernel<true><<<(ROWS + 3) / 4, 256, 0, stream>>>(h, lnb, ln2_g + i * 768, ln2_b + i * 768, ROWS);
        gemm_bf16<true, true, false, false, true, false><<<dim3(24, mt), 256, 0, stream>>>(
            lnb, wm1 + (size_t)i * 3072 * 768, mlp_b1 + i * 3072, mlpb, nullptr, ROWS, 3072, 768);
        gemm_bf16<true, false, true, false, false, false><<<dim3(6, mt), 256, 0, stream>>>(
            mlpb, wm2 + (size_t)i * 768 * 3072, mlp_b2 + i * 768, h, nullptr, ROWS, 768, 3072);
    }
    ln_kernel<false><<<(ROWS + 3) / 4, 256, 0, stream>>>(h, (float*)d_out, fin_g, fin_b, ROWS);
}

// Round 17
// 3571.285 us; speedup vs baseline: 1.0728x; 1.0148x over previous
//
#include <hip/hip_runtime.h>
#include <cmath>

#define NHEADS 12
#define NTOK   257
#define BATCH  32
#define ROWS   (BATCH*NTOK)   // 8224
#define PROWS  (BATCH*256)    // 8192
#define GTPAD  288            // padded key length for Vt

typedef __attribute__((ext_vector_type(8))) short short8;
typedef __attribute__((ext_vector_type(8))) unsigned short u16x8;
typedef __attribute__((ext_vector_type(4))) float f32x4;

__device__ __forceinline__ unsigned short f2bf(float f) {
    unsigned u = __float_as_uint(f);
    unsigned r = (u + 0x7FFFu + ((u >> 16) & 1u)) >> 16;
    return (unsigned short)r;
}
__device__ __forceinline__ float b2f(unsigned short us) {
    return __uint_as_float((unsigned)us << 16);
}
__device__ __forceinline__ void gload16(const void* g, void* l) {
    __builtin_amdgcn_global_load_lds(
        (const __attribute__((address_space(1))) void*)g,
        (__attribute__((address_space(3))) void*)l, 16, 0, 0);
}
// tanh-form GELU (|err| ~1e-3; ~10 VALU ops vs ~30 for libm erff)
__device__ __forceinline__ float gelu_f(float x) {
    float y = 0.7978845608f * (x + 0.044715f * x * x * x);
    float e = __expf(2.f * y);
    float t = 1.f - 2.f / (e + 1.f);
    return 0.5f * x * (1.f + t);
}

// ---------------------------------------------------------------------------
// bf16 MFMA GEMM (128x128 tile): 4 waves (2x2), wave 64x64, BK=128,
// SINGLE-buffered LDS (64KB): HALVED drain count per block (6 for K=768)
// — the only knob that moved wall time across R5-R16 (drain-count model).
// 16x16x32 MFMA, conflict-free XOR swizzle over 16-chunk space, XCD remap.
// VT: for col>=1536 (V part of qkv), write transposed into vt[bh][d][GTPAD].
// ---------------------------------------------------------------------------
template<bool BIAS, bool GELU, bool RES, bool SKIPAR, bool OUTBF, bool VT>
__global__ __launch_bounds__(256) void gemm_bf16(
    const unsigned short* __restrict__ A, const unsigned short* __restrict__ W,
    const float* __restrict__ bias, void* __restrict__ outv,
    unsigned short* __restrict__ vt,
    int M, int N, int K)
{
    __shared__ unsigned short As[128 * 128];
    __shared__ unsigned short Bs[128 * 128];
    const int tid = threadIdx.x;
    const int lane = tid & 63, wid = tid >> 6;
    const int wr = wid >> 1, wc = wid & 1;

    // bijective XCD-chunked remap (m204)
    const int gx = gridDim.x;
    const int nwg = gx * gridDim.y;
    const int orig = blockIdx.y * gx + blockIdx.x;
    const int q8 = nwg >> 3, r8 = nwg & 7;
    const int xcd = orig & 7, lid = orig >> 3;
    const int wg = (xcd < r8 ? xcd * (q8 + 1) : r8 * (q8 + 1) + (xcd - r8) * q8) + lid;
    const int bn = (wg % gx) * 128;
    const int bm = (wg / gx) * 128;

    f32x4 acc[4][4];
    #pragma unroll
    for (int i = 0; i < 4; i++)
        #pragma unroll
        for (int j = 0; j < 4; j++) acc[i][j] = (f32x4)0.f;

    const int l15 = lane & 15;
    const int lg  = lane >> 4;
    const int sw  = l15 & 7;

    const int nt = K >> 7;               // K-tiles of 128
    for (int t = 0; t < nt; t++) {
        int k0 = t << 7;
        #pragma unroll
        for (int it = 0; it < 8; it++) {
            int f = it * 256 + tid;      // 0..2047
            int row = f >> 4;            // 0..127
            int gc = (f & 15) ^ (row & 7);   // inverse-swizzled source chunk
            gload16(A + (size_t)(bm + row) * K + k0 + gc * 8, &As[f * 8]);
            gload16(W + (size_t)(bn + row) * K + k0 + gc * 8, &Bs[f * 8]);
        }
        __syncthreads();
        #pragma unroll
        for (int kk = 0; kk < 4; kk++) {
            short8 af[4], bf[4];
            #pragma unroll
            for (int i = 0; i < 4; i++) {
                int row = wr * 64 + i * 16 + l15;
                af[i] = *(const short8*)&As[row * 128 + (((kk * 4 + lg) ^ sw)) * 8];
            }
            #pragma unroll
            for (int j = 0; j < 4; j++) {
                int row = wc * 64 + j * 16 + l15;
                bf[j] = *(const short8*)&Bs[row * 128 + (((kk * 4 + lg) ^ sw)) * 8];
            }
            #pragma unroll
            for (int i = 0; i < 4; i++)
                #pragma unroll
                for (int j = 0; j < 4; j++)
                    acc[i][j] = __builtin_amdgcn_mfma_f32_16x16x32_bf16(af[i], bf[j], acc[i][j], 0, 0, 0);
        }
        __syncthreads();
    }

    float bcol[4];
    #pragma unroll
    for (int j = 0; j < 4; j++)
        bcol[j] = BIAS ? bias[bn + wc * 64 + j * 16 + l15] : 0.f;

    #pragma unroll
    for (int i = 0; i < 4; i++) {
        #pragma unroll
        for (int r = 0; r < 4; r++) {
            int row = bm + wr * 64 + i * 16 + lg * 4 + r;
            if (row >= M) continue;
            if (SKIPAR && (row % NTOK) == (NTOK - 1)) continue;
            int bb = 0, tok = 0;
            if (VT) { bb = row / NTOK; tok = row - bb * NTOK; }
            #pragma unroll
            for (int j = 0; j < 4; j++) {
                int col = bn + wc * 64 + j * 16 + l15;
                float v = acc[i][j][r] + bcol[j];
                if (GELU) v = gelu_f(v);
                size_t idx = (size_t)row * N + col;
                if (OUTBF) {
                    if (VT && col >= 1536) {
                        int c = col - 1536;
                        int nh = c >> 6, d = c & 63;
                        vt[(size_t)((bb * NHEADS + nh) * 64 + d) * GTPAD + tok] = f2bf(v);
                    } else {
                        ((unsigned short*)outv)[idx] = f2bf(v);
                    }
                } else {
                    float* o = (float*)outv;
                    if (RES) o[idx] += v; else o[idx] = v;
                }
            }
        }
    }
}

// ---------------------------------------------------------------------------
// Zero the Vt pad region (tokens 256..287). Launched ONCE per call.
// ---------------------------------------------------------------------------
__global__ __launch_bounds__(256) void zero_vt_pad(unsigned short* __restrict__ vt)
{
    int t = blockIdx.x * 256 + threadIdx.x;      // 0 .. 384*64*4-1
    int bhd = t >> 2, ch = t & 3;
    *(uint4*)(vt + (size_t)bhd * GTPAD + 256 + ch * 8) = make_uint4(0u, 0u, 0u, 0u);
}

// ---------------------------------------------------------------------------
// LayerNorm: one wave per row of 768. Input fp32, output fp32 or bf16.
// ---------------------------------------------------------------------------
template<bool OUTBF>
__global__ __launch_bounds__(256) void ln_kernel(
    const float* __restrict__ in, void* __restrict__ outv,
    const float* __restrict__ g, const float* __restrict__ bparm, int rows)
{
    int gw = blockIdx.x * 4 + (threadIdx.x >> 6);
    int lane = threadIdx.x & 63;
    if (gw >= rows) return;
    const float* x = in + (size_t)gw * 768;
    float4 v[3];
    #pragma unroll
    for (int i = 0; i < 3; i++) v[i] = *(const float4*)(x + i * 256 + lane * 4);
    float s = 0.f;
    #pragma unroll
    for (int i = 0; i < 3; i++) s += v[i].x + v[i].y + v[i].z + v[i].w;
    #pragma unroll
    for (int off = 32; off >= 1; off >>= 1) s += __shfl_xor(s, off, 64);
    float mu = s * (1.f / 768.f);
    float q = 0.f;
    #pragma unroll
    for (int i = 0; i < 3; i++) {
        float dx = v[i].x - mu, dy = v[i].y - mu, dz = v[i].z - mu, dw = v[i].w - mu;
        q += dx * dx + dy * dy + dz * dz + dw * dw;
    }
    #pragma unroll
    for (int off = 32; off >= 1; off >>= 1) q += __shfl_xor(q, off, 64);
    float rstd = rsqrtf(q * (1.f / 768.f) + 1e-5f);
    #pragma unroll
    for (int i = 0; i < 3; i++) {
        float4 gg = *(const float4*)(g + i * 256 + lane * 4);
        float4 bb = *(const float4*)(bparm + i * 256 + lane * 4);
        float rx = (v[i].x - mu) * rstd * gg.x + bb.x;
        float ry = (v[i].y - mu) * rstd * gg.y + bb.y;
        float rz = (v[i].z - mu) * rstd * gg.z + bb.z;
        float rw = (v[i].w - mu) * rstd * gg.w + bb.w;
        if (OUTBF) {
            ushort4 u;
            u.x = f2bf(rx); u.y = f2bf(ry); u.z = f2bf(rz); u.w = f2bf(rw);
            *(ushort4*)((unsigned short*)outv + (size_t)gw * 768 + i * 256 + lane * 4) = u;
        } else {
            *(float4*)((float*)outv + (size_t)gw * 768 + i * 256 + lane * 4) =
                make_float4(rx, ry, rz, rw);
        }
    }
}

// ---------------------------------------------------------------------------
__global__ __launch_bounds__(256) void f2b_kernel(
    const float* __restrict__ in, unsigned short* __restrict__ out, int n4)
{
    int i = blockIdx.x * 256 + threadIdx.x;
    if (i >= n4) return;
    float4 v = ((const float4*)in)[i];
    ushort4 u;
    u.x = f2bf(v.x); u.y = f2bf(v.y); u.z = f2bf(v.z); u.w = f2bf(v.w);
    ((ushort4*)out)[i] = u;
}

// ---------------------------------------------------------------------------
__global__ __launch_bounds__(256) void gather_patches(
    const float* __restrict__ x, unsigned short* __restrict__ A)
{
    int row = blockIdx.x;                 // 0..8191
    int b = row >> 8;
    int pp = row & 255;
    int ph = pp >> 4, pw = pp & 15;
    const float* xb = x + (size_t)b * 196608;
    for (int e = threadIdx.x; e < 768; e += 256) {
        int c = e >> 8;
        int r = e & 255;
        int p = r >> 4, q = r & 15;
        A[(size_t)row * 768 + e] = f2bf(xb[(size_t)c * 65536 + (ph * 16 + p) * 256 + pw * 16 + q]);
    }
}

// ---------------------------------------------------------------------------
__global__ __launch_bounds__(256) void build_h_kernel(
    const unsigned short* __restrict__ lnp, const float* __restrict__ pos,
    const float* __restrict__ artok, const float* __restrict__ aspect,
    float* __restrict__ h)
{
    int row = blockIdx.x;                 // 0..8223
    int b = row / NTOK;
    int t = row - b * NTOK;
    float* hp = h + (size_t)row * 768;
    int e = threadIdx.x;
    if (t < 256) {
        const unsigned short* lp = lnp + ((size_t)b * 256 + t) * 768;
        const float* pp = pos + (size_t)t * 768;
        #pragma unroll
        for (int i = 0; i < 3; i++) { int c = e + i * 256; hp[c] = b2f(lp[c]) + pp[c]; }
    } else {
        float f = 1.0f + aspect[b] * 0.1f;
        const float* pp = pos + (size_t)256 * 768;
        #pragma unroll
        for (int i = 0; i < 3; i++) { int c = e + i * 256; hp[c] = artok[c] * f + pp[c]; }
    }
}

// ---------------------------------------------------------------------------
// Local windowed attention, MFMA. One wave per (b,head,image-row h0).
// ---------------------------------------------------------------------------
__global__ __launch_bounds__(256) void local_attn_mfma(
    const unsigned short* __restrict__ qkv, const unsigned short* __restrict__ vt,
    unsigned short* __restrict__ out)
{
    __shared__ unsigned short P[4][16 * 136];        // per-wave P slab, stride 272B
    const int wid = threadIdx.x >> 6, lane = threadIdx.x & 63;
    const int gw = blockIdx.x * 4 + wid;
    const int bh = gw >> 4, h0 = gw & 15;
    const int b = bh / NHEADS, nh = bh % NHEADS;
    const int l15 = lane & 15, lg = lane >> 4;
    const unsigned short* base = qkv + (size_t)b * NTOK * 2304 + nh * 64;
    const unsigned short* vtb = vt + (size_t)bh * 64 * GTPAD;
    unsigned short* Pw = P[wid];

    const int qtok = h0 * 16 + l15;
    short8 qf0 = *(const short8*)(base + (size_t)qtok * 2304 + lg * 8);
    short8 qf1 = *(const short8*)(base + (size_t)qtok * 2304 + 32 + lg * 8);

    int r0 = h0 - 3; r0 = r0 < 0 ? 0 : (r0 > 8 ? 8 : r0);   // 8 key rows r0..r0+7

    f32x4 s[8];
    #pragma unroll
    for (int i = 0; i < 8; i++) {
        const unsigned short* kr = base + (size_t)((r0 + i) * 16 + l15) * 2304 + 768;
        short8 kf0 = *(const short8*)(kr + lg * 8);
        short8 kf1 = *(const short8*)(kr + 32 + lg * 8);
        f32x4 z = (f32x4)0.f;
        z = __builtin_amdgcn_mfma_f32_16x16x32_bf16(kf0, qf0, z, 0, 0, 0);
        z = __builtin_amdgcn_mfma_f32_16x16x32_bf16(kf1, qf1, z, 0, 0, 0);
        s[i] = z;
    }

    const int vlo = l15 - 3 < 0 ? 0 : l15 - 3;
    const int vhi = l15 + 3 > 15 ? 15 : l15 + 3;
    const int rlo = h0 - 3 < 0 ? 0 : h0 - 3;
    const int rhi = h0 + 3 > 15 ? 15 : h0 + 3;
    const int n_oob = 49 - (rhi - rlo + 1) * (vhi - vlo + 1);
    float m = n_oob > 0 ? 0.f : -1e30f;
    float sv[32];
    #pragma unroll
    for (int i = 0; i < 8; i++) {
        int kh = r0 + i;
        bool rowok = (kh >= rlo) && (kh <= rhi);
        #pragma unroll
        for (int r = 0; r < 4; r++) {
            int kw = lg * 4 + r;
            bool ok = rowok && (kw >= vlo) && (kw <= vhi);
            float xx = ok ? s[i][r] * 0.125f : -1e30f;
            sv[i * 4 + r] = xx;
            m = fmaxf(m, xx);
        }
    }
    m = fmaxf(m, __shfl_xor(m, 16, 64));
    m = fmaxf(m, __shfl_xor(m, 32, 64));
    float tsum = 0.f;
    #pragma unroll
    for (int i = 0; i < 8; i++) {
        float p0 = __expf(sv[i * 4 + 0] - m);
        float p1 = __expf(sv[i * 4 + 1] - m);
        float p2 = __expf(sv[i * 4 + 2] - m);
        float p3 = __expf(sv[i * 4 + 3] - m);
        tsum += p0 + p1 + p2 + p3;
        unsigned u0 = (unsigned)f2bf(p0) | ((unsigned)f2bf(p1) << 16);
        unsigned u1 = (unsigned)f2bf(p2) | ((unsigned)f2bf(p3) << 16);
        *(uint2*)((char*)Pw + l15 * 272 + i * 32 + lg * 8) = make_uint2(u0, u1);
    }
    tsum += __shfl_xor(tsum, 16, 64);
    tsum += __shfl_xor(tsum, 32, 64);
    float denom = tsum + (float)n_oob * __expf(-m);
    __syncthreads();

    f32x4 acc[4];
    #pragma unroll
    for (int d = 0; d < 4; d++) acc[d] = (f32x4)0.f;
    #pragma unroll
    for (int kt = 0; kt < 128; kt += 32) {
        short8 pf = *(const short8*)((char*)Pw + l15 * 272 + kt * 2 + lg * 16);
        #pragma unroll
        for (int d = 0; d < 4; d++) {
            short8 vf = *(const short8*)(vtb + (size_t)(d * 16 + l15) * GTPAD + r0 * 16 + kt + lg * 8);
            acc[d] = __builtin_amdgcn_mfma_f32_16x16x32_bf16(vf, pf, acc[d], 0, 0, 0);
        }
    }

    float inv = 1.f / denom;
    unsigned short* op = out + ((size_t)b * NTOK + qtok) * 768 + nh * 64;
    #pragma unroll
    for (int d = 0; d < 4; d++) {
        ushort4 o;
        o.x = f2bf(acc[d][0] * inv);
        o.y = f2bf(acc[d][1] * inv);
        o.z = f2bf(acc[d][2] * inv);
        o.w = f2bf(acc[d][3] * inv);
        *(ushort4*)(op + d * 16 + lg * 4) = o;
    }
}

// ---------------------------------------------------------------------------
// Global attention, MFMA flash. One wave per (head, 16-query tile).
// ---------------------------------------------------------------------------
__global__ __launch_bounds__(64) void global_attn_mfma(
    const unsigned short* __restrict__ qkv, const unsigned short* __restrict__ vt,
    unsigned short* __restrict__ out)
{
    __shared__ uint4 Pbuf[80];                       // 16 q * 40 ushort (pad)
    unsigned short* P = (unsigned short*)Pbuf;
    const int blk = blockIdx.x;
    const int bh = blk / 17, qt = blk % 17;
    const int b = bh / NHEADS, nh = bh % NHEADS;
    const int lane = threadIdx.x;
    const int l15 = lane & 15, lg = lane >> 4;
    const unsigned short* base = qkv + (size_t)b * NTOK * 2304 + nh * 64;
    const unsigned short* vtb = vt + (size_t)bh * 64 * GTPAD;

    int qrow = qt * 16 + l15;
    const bool qvalid = qrow < NTOK;
    if (!qvalid) qrow = NTOK - 1;
    short8 qf[2];
    qf[0] = *(const short8*)(base + (size_t)qrow * 2304 + lg * 8);
    qf[1] = *(const short8*)(base + (size_t)qrow * 2304 + 32 + lg * 8);

    f32x4 acc[4];
    #pragma unroll
    for (int i = 0; i < 4; i++) acc[i] = (f32x4)0.f;
    float m = -1e30f, l = 0.f;

    for (int kt = 0; kt < GTPAD; kt += 32) {
        f32x4 s[2];
        #pragma unroll
        for (int hh = 0; hh < 2; hh++) {
            int krow = kt + hh * 16 + l15;
            if (krow > NTOK - 1) krow = NTOK - 1;
            short8 kf0 = *(const short8*)(base + (size_t)krow * 2304 + 768 + lg * 8);
            short8 kf1 = *(const short8*)(base + (size_t)krow * 2304 + 768 + 32 + lg * 8);
            f32x4 z = (f32x4)0.f;
            z = __builtin_amdgcn_mfma_f32_16x16x32_bf16(kf0, qf[0], z, 0, 0, 0);
            z = __builtin_amdgcn_mfma_f32_16x16x32_bf16(kf1, qf[1], z, 0, 0, 0);
            s[hh] = z;
        }
        float sv[8];
        float mt = -1e30f;
        #pragma unroll
        for (int hh = 0; hh < 2; hh++)
            #pragma unroll
            for (int r = 0; r < 4; r++) {
                int key = kt + hh * 16 + lg * 4 + r;
                float v = s[hh][r] * 0.125f;
                if (key >= NTOK) v = -1e30f;
                sv[hh * 4 + r] = v;
                mt = fmaxf(mt, v);
            }
        mt = fmaxf(mt, __shfl_xor(mt, 16, 64));
        mt = fmaxf(mt, __shfl_xor(mt, 32, 64));
        float mn = fmaxf(m, mt);
        float cf = __expf(m - mn);
        float tsum = 0.f;
        unsigned short pb[8];
        #pragma unroll
        for (int i = 0; i < 8; i++) {
            float p = __expf(sv[i] - mn);
            tsum += p;
            pb[i] = f2bf(p);
        }
        tsum += __shfl_xor(tsum, 16, 64);
        tsum += __shfl_xor(tsum, 32, 64);
        l = l * cf + tsum;
        m = mn;
        #pragma unroll
        for (int i = 0; i < 4; i++) acc[i] *= cf;

        unsigned u0 = (unsigned)pb[0] | ((unsigned)pb[1] << 16);
        unsigned u1 = (unsigned)pb[2] | ((unsigned)pb[3] << 16);
        unsigned u2 = (unsigned)pb[4] | ((unsigned)pb[5] << 16);
        unsigned u3 = (unsigned)pb[6] | ((unsigned)pb[7] << 16);
        *(uint2*)((char*)P + l15 * 80 + lg * 8)      = make_uint2(u0, u1);
        *(uint2*)((char*)P + l15 * 80 + 32 + lg * 8) = make_uint2(u2, u3);
        __syncthreads();
        short8 pf = *(const short8*)((char*)P + l15 * 80 + lg * 16);
        #pragma unroll
        for (int d = 0; d < 4; d++) {
            short8 vf = *(const short8*)(vtb + (size_t)(d * 16 + l15) * GTPAD + kt + lg * 8);
            acc[d] = __builtin_amdgcn_mfma_f32_16x16x32_bf16(vf, pf, acc[d], 0, 0, 0);
        }
        __syncthreads();
    }

    if (qvalid) {
        float inv = 1.f / l;
        unsigned short* op = out + ((size_t)b * NTOK + qrow) * 768 + nh * 64;
        #pragma unroll
        for (int d = 0; d < 4; d++) {
            ushort4 o;
            o.x = f2bf(acc[d][0] * inv);
            o.y = f2bf(acc[d][1] * inv);
            o.z = f2bf(acc[d][2] * inv);
            o.w = f2bf(acc[d][3] * inv);
            *(ushort4*)(op + d * 16 + lg * 4) = o;
        }
    }
}

// ---------------------------------------------------------------------------
extern "C" void kernel_launch(void* const* d_in, const int* in_sizes, int n_in,
                              void* d_out, int out_size, void* d_ws, size_t ws_size,
                              hipStream_t stream)
{
    const float* x       = (const float*)d_in[0];
    const float* aspect  = (const float*)d_in[1];
    const float* conv_w  = (const float*)d_in[2];
    const float* conv_b  = (const float*)d_in[3];
    const float* pe_g    = (const float*)d_in[4];
    const float* pe_b    = (const float*)d_in[5];
    const float* ar_tok  = (const float*)d_in[6];
    const float* pos     = (const float*)d_in[7];
    const float* ln1_g   = (const float*)d_in[8];
    const float* ln1_b   = (const float*)d_in[9];
    const float* ln2_g   = (const float*)d_in[10];
    const float* ln2_b   = (const float*)d_in[11];
    const float* loc_qkv_w  = (const float*)d_in[12];
    const float* loc_proj_w = (const float*)d_in[13];
    const float* loc_proj_b = (const float*)d_in[14];
    const float* glob_in_w  = (const float*)d_in[15];
    const float* glob_in_b  = (const float*)d_in[16];
    const float* glob_out_w = (const float*)d_in[17];
    const float* glob_out_b = (const float*)d_in[18];
    const float* mlp_w1  = (const float*)d_in[19];
    const float* mlp_b1  = (const float*)d_in[20];
    const float* mlp_w2  = (const float*)d_in[21];
    const float* mlp_b2  = (const float*)d_in[22];
    const float* fin_g   = (const float*)d_in[23];
    const float* fin_b   = (const float*)d_in[24];

    char* w = (char*)d_ws;
    float*          h     = (float*)w;                                   // 25,264,128 B
    unsigned short* lnb   = (unsigned short*)(w + 25264128);             // 12,632,064 B
    unsigned short* qkvb  = (unsigned short*)(w + 37896192);             // 37,896,192 B
    unsigned short* attnb = (unsigned short*)(w + 75792384);             // 12,632,064 B
    unsigned short* mlpb  = (unsigned short*)(w + 88424448);             // 50,528,256 B
    float*          pembf = (float*)mlpb;                                // aliased (pre-loop only)
    unsigned short* vtb   = (unsigned short*)(w + 124796928);            // tail of mlpb, 14.2 MB
    char* wp = w + 138952704;
    unsigned short* wconv  = (unsigned short*)wp;               wp += 1179648;
    unsigned short* wlqkv  = (unsigned short*)wp;               wp += 21233664;
    unsigned short* wlproj = (unsigned short*)wp;               wp += 7077888;
    unsigned short* wgin   = (unsigned short*)wp;               wp += 21233664;
    unsigned short* wgout  = (unsigned short*)wp;               wp += 7077888;
    unsigned short* wm1    = (unsigned short*)wp;               wp += 56623104;
    unsigned short* wm2    = (unsigned short*)wp;               wp += 56623104;

    auto cvt = [&](const float* src, unsigned short* dst, int n) {
        int n4 = n / 4;
        f2b_kernel<<<(n4 + 255) / 256, 256, 0, stream>>>(src, dst, n4);
    };
    cvt(conv_w,     wconv,  768 * 768);
    cvt(loc_qkv_w,  wlqkv,  6 * 2304 * 768);
    cvt(loc_proj_w, wlproj, 6 * 768 * 768);
    cvt(glob_in_w,  wgin,   6 * 2304 * 768);
    cvt(glob_out_w, wgout,  6 * 768 * 768);
    cvt(mlp_w1,     wm1,    12 * 3072 * 768);
    cvt(mlp_w2,     wm2,    12 * 768 * 3072);

    // ---- patch embed ----
    gather_patches<<<PROWS, 256, 0, stream>>>(x, qkvb);
    gemm_bf16<true, false, false, false, false, false><<<dim3(6, 64), 256, 0, stream>>>(
        qkvb, wconv, conv_b, pembf, nullptr, PROWS, 768, 768);
    ln_kernel<true><<<PROWS / 4, 256, 0, stream>>>(pembf, attnb, pe_g, pe_b, PROWS);
    build_h_kernel<<<ROWS, 256, 0, stream>>>(attnb, pos, ar_tok, aspect, h);
    zero_vt_pad<<<384, 256, 0, stream>>>(vtb);   // pad tokens stay 0 across layers

    const int mt = (ROWS + 127) / 128;    // 65
    for (int i = 0; i < 12; i++) {
        int half = i / 2;
        ln_kernel<true><<<(ROWS + 3) / 4, 256, 0, stream>>>(h, lnb, ln1_g + i * 768, ln1_b + i * 768, ROWS);
        if ((i & 1) == 0) {
            gemm_bf16<false, false, false, false, true, true><<<dim3(18, mt), 256, 0, stream>>>(
                lnb, wlqkv + (size_t)half * 2304 * 768, nullptr, qkvb, vtb, ROWS, 2304, 768);
            local_attn_mfma<<<BATCH * NHEADS * 16 / 4, 256, 0, stream>>>(qkvb, vtb, attnb);
            gemm_bf16<true, false, true, true, false, false><<<dim3(6, mt), 256, 0, stream>>>(
                attnb, wlproj + (size_t)half * 768 * 768, loc_proj_b + half * 768, h, nullptr, ROWS, 768, 768);
        } else {
            gemm_bf16<true, false, false, false, true, true><<<dim3(18, mt), 256, 0, stream>>>(
                lnb, wgin + (size_t)half * 2304 * 768, glob_in_b + half * 2304, qkvb, vtb, ROWS, 2304, 768);
            global_attn_mfma<<<BATCH * NHEADS * 17, 64, 0, stream>>>(qkvb, vtb, attnb);
            gemm_bf16<true, false, true, false, false, false><<<dim3(6, mt), 256, 0, stream>>>(
                attnb, wgout + (size_t)half * 768 * 768, glob_out_b + half * 768, h, nullptr, ROWS, 768, 768);
        }
        ln_kernel<true><<<(ROWS + 3) / 4, 256, 0, stream>>>(h, lnb, ln2_g + i * 768, ln2_b + i * 768, ROWS);
        gemm_bf16<true, true, false, false, true, false><<<dim3(24, mt), 256, 0, stream>>>(
            lnb, wm1 + (size_t)i * 3072 * 768, mlp_b1 + i * 3072, mlpb, nullptr, ROWS, 3072, 768);
        gemm_bf16<true, false, true, false, false, false><<<dim3(6, mt), 256, 0, stream>>>(
            mlpb, wm2 + (size_t)i * 768 * 3072, mlp_b2 + i * 768, h, nullptr, ROWS, 768, 3072);
    }
    ln_kernel<false><<<(ROWS + 3) / 4, 256, 0, stream>>>(h, (float*)d_out, fin_g, fin_b, ROWS);
}